// Round 5
// baseline (993.276 us; speedup 1.0000x reference)
//
#include <hip/hip_runtime.h>
#include <math.h>

#define BB 2
#define LL 8
#define HH 240
#define WW 320
#define NN (HH*WW)      // 76800
#define MM (LL*NN)      // 614400

#define DIST_TH 0.05f
#define DOT_TH  0.9396926207859084f   // cos(20 deg)
#define SIGMA   0.6f
#define EPSF    1e-8f
#define SENTINEL 0x7F7F7F7F

#define NB 512          // persistent blocks (<= half residency capacity)
#define NT 256
#define NTH (NB*NT)

// ---------------------------------------------------------------------------
__device__ __forceinline__ float backproject(
    const float* __restrict__ dep,
    float fx, float fy, float cx, float cy,
    const float* __restrict__ P,
    int h, int w, float o[3])
{
    float d  = dep[h*WW + w];
    float gx = ((float)w - cx) / fx;
    float gy = ((float)h - cy) / fy;
    float px = gx*d, py = gy*d, pz = d;
    o[0] = P[0]*px + P[1]*py + P[2]*pz  + P[3];
    o[1] = P[4]*px + P[5]*py + P[6]*pz  + P[7];
    o[2] = P[8]*px + P[9]*py + P[10]*pz + P[11];
    return d;
}

__device__ __forceinline__ void frame_data(
    const float* __restrict__ rgb, const float* __restrict__ depth,
    const float* __restrict__ intr, const float* __restrict__ poses,
    int b, int s, int n,
    float fpos[3], float fn[3], float fcol[3], float& falpha, bool& fvalid)
{
    const float* Km = intr + b*16;
    float fx = Km[0], fy = Km[5], cx = Km[2], cy = Km[6];
    const float* P  = poses + (b*LL + s)*16;
    const float* dep = depth + ((size_t)(b*LL + s))*NN;

    int h = n / WW, w = n % WW;

    float p0[3], tmp[3], dx[3], dy[3];
    float d = backproject(dep, fx, fy, cx, cy, P, h, w, p0);

    if (w < WW-1) { backproject(dep, fx, fy, cx, cy, P, h, w+1, tmp);
                    dx[0]=tmp[0]-p0[0]; dx[1]=tmp[1]-p0[1]; dx[2]=tmp[2]-p0[2]; }
    else          { backproject(dep, fx, fy, cx, cy, P, h, WW-2, tmp);
                    dx[0]=p0[0]-tmp[0]; dx[1]=p0[1]-tmp[1]; dx[2]=p0[2]-tmp[2]; }

    if (h < HH-1) { backproject(dep, fx, fy, cx, cy, P, h+1, w, tmp);
                    dy[0]=tmp[0]-p0[0]; dy[1]=tmp[1]-p0[1]; dy[2]=tmp[2]-p0[2]; }
    else          { backproject(dep, fx, fy, cx, cy, P, HH-2, w, tmp);
                    dy[0]=p0[0]-tmp[0]; dy[1]=p0[1]-tmp[1]; dy[2]=p0[2]-tmp[2]; }

    float nx = dx[1]*dy[2] - dx[2]*dy[1];
    float ny = dx[2]*dy[0] - dx[0]*dy[2];
    float nz = dx[0]*dy[1] - dx[1]*dy[0];
    float nl = sqrtf(nx*nx + ny*ny + nz*nz) + EPSF;
    fn[0] = nx/nl; fn[1] = ny/nl; fn[2] = nz/nl;

    fpos[0]=p0[0]; fpos[1]=p0[1]; fpos[2]=p0[2];

    const float* c = rgb + (((size_t)(b*LL + s))*NN + n)*3;
    fcol[0]=c[0]; fcol[1]=c[1]; fcol[2]=c[2];

    float gx = ((float)w - cx)/fx, gy = ((float)h - cy)/fy;
    falpha = expf(-(gx*gx + gy*gy) / (2.0f*SIGMA*SIGMA));
    fvalid = d > 0.0f;
}

// ---------------------------------------------------------------------------
// Hand-rolled grid barrier. Sense = generation counter. Every thread fences
// execution via __syncthreads (drains vmcnt); wave 0 does the agent-scope
// cache ops (__threadfence -> wbl2/inv on gfx9xx) and the arrival/spin.
// ---------------------------------------------------------------------------
__device__ __forceinline__ void gridbar(int* cnt, int* gen)
{
    __syncthreads();                       // all block stores issued+drained
    if (threadIdx.x == 0) {
        __threadfence();                   // release: L2 writeback (agent scope)
        int g = __hip_atomic_load(gen, __ATOMIC_RELAXED, __HIP_MEMORY_SCOPE_AGENT);
        int prev = __hip_atomic_fetch_add(cnt, 1, __ATOMIC_RELAXED, __HIP_MEMORY_SCOPE_AGENT);
        if (prev == NB-1) {
            __hip_atomic_store(cnt, 0, __ATOMIC_RELAXED, __HIP_MEMORY_SCOPE_AGENT);
            __hip_atomic_fetch_add(gen, 1, __ATOMIC_RELAXED, __HIP_MEMORY_SCOPE_AGENT);
        } else {
            while (__hip_atomic_load(gen, __ATOMIC_RELAXED, __HIP_MEMORY_SCOPE_AGENT) == g)
                __builtin_amdgcn_s_sleep(1);
        }
        __threadfence();                   // acquire: L1/L2 invalidate
    }
    __syncthreads();
}

__global__ void k_barinit(int* bar) { bar[0] = 0; bar[1] = 0; }

// ---------------------------------------------------------------------------
// One persistent kernel: init phase, then 7 x (project, fuse) with barriers.
// ---------------------------------------------------------------------------
__global__ __launch_bounds__(NT, 2) void k_all(
    const float* __restrict__ rgb, const float* __restrict__ depth,
    const float* __restrict__ intr, const float* __restrict__ poses,
    float* __restrict__ map, float4* __restrict__ posconf,
    int* __restrict__ corr, int* __restrict__ bar)
{
    const int gtid = blockIdx.x*NT + threadIdx.x;
    int* cnt = bar + 0;
    int* gen = bar + 1;

    // ---- Phase 0: frame-0 rows + posconf + corr sentinel ------------------
    for (int k = gtid; k < BB*NN; k += NTH) {
        int b = (k >= NN) ? 1 : 0;
        int n = k - b*NN;
        float fpos[3], fn[3], fcol[3], fa; bool fv;
        frame_data(rgb, depth, intr, poses, b, 0, n, fpos, fn, fcol, fa, fv);
        float2* r2 = (float2*)(map + ((size_t)b*MM + n)*10);
        if (fv) {
            r2[0] = make_float2(fpos[0], fpos[1]);
            r2[1] = make_float2(fpos[2], fn[0]);
            r2[2] = make_float2(fn[1],  fn[2]);
            r2[3] = make_float2(fcol[0], fcol[1]);
            r2[4] = make_float2(fcol[2], fa);
            posconf[(size_t)b*MM + n] = make_float4(fpos[0], fpos[1], fpos[2], fa);
        } else {
            float2 z = make_float2(0.f,0.f);
            r2[0]=z; r2[1]=z; r2[2]=z; r2[3]=z; r2[4]=z;
            posconf[(size_t)b*MM + n] = make_float4(0.f,0.f,0.f,0.f);
        }
        corr[k] = SENTINEL;
    }
    gridbar(cnt, gen);

    for (int s = 1; s < LL; ++s) {
        // ---- project: rows [0, s*N) -> frame s, scatter-min ---------------
        const int lim = s*NN;
        for (int k = gtid; k < BB*lim; k += NTH) {
            int b = (k >= lim) ? 1 : 0;
            int i = k - b*lim;
            float4 pc4 = posconf[(size_t)b*MM + i];
            if (!(pc4.w > 0.0f)) continue;

            const float* Km = intr + b*16;
            float fx = Km[0], fy = Km[5], cx = Km[2], cy = Km[6];
            const float* P  = poses + (b*LL + s)*16;

            float d0 = pc4.x-P[3], d1 = pc4.y-P[7], d2 = pc4.z-P[11];
            float pcx = d0*P[0] + d1*P[4] + d2*P[8];
            float pcy = d0*P[1] + d1*P[5] + d2*P[9];
            float pcz = d0*P[2] + d1*P[6] + d2*P[10];
            if (!(pcz > EPSF)) continue;

            float uf = rintf(fx*pcx/pcz + cx);   // half-to-even = jnp.round
            float vf = rintf(fy*pcy/pcz + cy);
            if (!(uf >= 0.0f && uf <= (float)(WW-1) &&
                  vf >= 0.0f && vf <= (float)(HH-1))) continue;
            int ui = (int)uf, vi = (int)vf;
            atomicMin(&corr[b*NN + vi*WW + ui], i);   // device-scope
        }
        gridbar(cnt, gen);

        // ---- fuse + append ------------------------------------------------
        for (int k = gtid; k < BB*NN; k += NTH) {
            int b = (k >= NN) ? 1 : 0;
            int n = k - b*NN;

            float fpos[3], fn[3], fcol[3], fa; bool fv;
            frame_data(rgb, depth, intr, poses, b, s, n, fpos, fn, fcol, fa, fv);

            int cv = corr[k];
            corr[k] = SENTINEL;     // owner-reset for next step

            bool match = false;
            if (cv < MM && fv) {
                int ci = cv;        // unique winner per pixel
                float2* c2 = (float2*)(map + ((size_t)b*MM + ci)*10);
                float2 a0 = c2[0], a1 = c2[1], a2 = c2[2], a3 = c2[3], a4 = c2[4];
                float cp0=a0.x, cp1=a0.y, cp2=a1.x;
                float cn0=a1.y, cn1=a2.x, cn2=a2.y;
                float cc0=a3.x, cc1=a3.y, cc2=a4.x;
                float cw =a4.y;

                float e0 = fpos[0]-cp0, e1 = fpos[1]-cp1, e2 = fpos[2]-cp2;
                float dist = sqrtf(e0*e0 + e1*e1 + e2*e2);
                float dotp = fn[0]*cn0 + fn[1]*cn1 + fn[2]*cn2;

                if (dist < DIST_TH && dotp > DOT_TH) {
                    match = true;
                    float wgt = fa;
                    float den = cw + wgt;
                    float np0 = (cw*cp0 + wgt*fpos[0]) / den;
                    float np1 = (cw*cp1 + wgt*fpos[1]) / den;
                    float np2 = (cw*cp2 + wgt*fpos[2]) / den;
                    float nc0 = (cw*cc0 + wgt*fcol[0]) / den;
                    float nc1 = (cw*cc1 + wgt*fcol[1]) / den;
                    float nc2 = (cw*cc2 + wgt*fcol[2]) / den;
                    float nn0 = cw*cn0 + wgt*fn[0];
                    float nn1 = cw*cn1 + wgt*fn[1];
                    float nn2 = cw*cn2 + wgt*fn[2];
                    float nl  = sqrtf(nn0*nn0 + nn1*nn1 + nn2*nn2) + EPSF;
                    c2[0] = make_float2(np0, np1);
                    c2[1] = make_float2(np2, nn0/nl);
                    c2[2] = make_float2(nn1/nl, nn2/nl);
                    c2[3] = make_float2(nc0, nc1);
                    c2[4] = make_float2(nc2, den);
                    posconf[(size_t)b*MM + ci] = make_float4(np0, np1, np2, den);
                }
            }

            size_t slot = (size_t)b*MM + (size_t)s*NN + n;
            float2* s2 = (float2*)(map + slot*10);
            if (fv && !match) {
                s2[0] = make_float2(fpos[0], fpos[1]);
                s2[1] = make_float2(fpos[2], fn[0]);
                s2[2] = make_float2(fn[1],  fn[2]);
                s2[3] = make_float2(fcol[0], fcol[1]);
                s2[4] = make_float2(fcol[2], fa);
                posconf[slot] = make_float4(fpos[0], fpos[1], fpos[2], fa);
            } else {
                float2 z = make_float2(0.f,0.f);
                s2[0]=z; s2[1]=z; s2[2]=z; s2[3]=z; s2[4]=z;
                posconf[slot] = make_float4(0.f,0.f,0.f,0.f);
            }
        }
        if (s < LL-1) gridbar(cnt, gen);   // no barrier needed after last fuse
    }
}

// ---------------------------------------------------------------------------
extern "C" void kernel_launch(void* const* d_in, const int* in_sizes, int n_in,
                              void* d_out, int out_size, void* d_ws, size_t ws_size,
                              hipStream_t stream) {
    const float* rgb   = (const float*)d_in[0];  // (B,L,H,W,3)
    const float* depth = (const float*)d_in[1];  // (B,L,H,W,1)
    const float* intr  = (const float*)d_in[2];  // (B,1,4,4)
    const float* poses = (const float*)d_in[3];  // (B,L,4,4)
    float* map = (float*)d_out;                  // (B,M,10)

    float4* posconf = (float4*)d_ws;                                      // B*M float4
    int*    corr    = (int*)((char*)d_ws + (size_t)BB*MM*sizeof(float4)); // B*N ints
    int*    bar     = corr + BB*NN;                                       // 2 ints

    k_barinit<<<1, 1, 0, stream>>>(bar);
    k_all<<<NB, NT, 0, stream>>>(rgb, depth, intr, poses, map, posconf, corr, bar);
}

// Round 6
// 158.682 us; speedup vs baseline: 6.2595x; 6.2595x over previous
//
#include <hip/hip_runtime.h>
#include <math.h>

#define BB 2
#define LL 8
#define HH 240
#define WW 320
#define NN (HH*WW)      // 76800
#define MM (LL*NN)      // 614400

#define DIST_TH 0.05f
#define DOT_TH  0.9396926207859084f   // cos(20 deg)
#define SIGMA   0.6f
#define EPSF    1e-8f
#define SENTINEL 0x7F7F7F7F
#define NOPIX   0xFFFFF

// ---------------------------------------------------------------------------
__device__ __forceinline__ float backproject(
    const float* __restrict__ dep,
    float fx, float fy, float cx, float cy,
    const float* __restrict__ P,
    int h, int w, float o[3])
{
    float d  = dep[h*WW + w];
    float gx = ((float)w - cx) / fx;
    float gy = ((float)h - cy) / fy;
    float px = gx*d, py = gy*d, pz = d;
    o[0] = P[0]*px + P[1]*py + P[2]*pz  + P[3];
    o[1] = P[4]*px + P[5]*py + P[6]*pz  + P[7];
    o[2] = P[8]*px + P[9]*py + P[10]*pz + P[11];
    return d;
}

__device__ __forceinline__ void frame_data(
    const float* __restrict__ rgb, const float* __restrict__ depth,
    const float* __restrict__ intr, const float* __restrict__ poses,
    int b, int s, int n,
    float fpos[3], float fn[3], float fcol[3], float& falpha, bool& fvalid)
{
    const float* Km = intr + b*16;
    float fx = Km[0], fy = Km[5], cx = Km[2], cy = Km[6];
    const float* P  = poses + (b*LL + s)*16;
    const float* dep = depth + ((size_t)(b*LL + s))*NN;

    int h = n / WW, w = n % WW;

    float p0[3], tmp[3], dx[3], dy[3];
    float d = backproject(dep, fx, fy, cx, cy, P, h, w, p0);

    if (w < WW-1) { backproject(dep, fx, fy, cx, cy, P, h, w+1, tmp);
                    dx[0]=tmp[0]-p0[0]; dx[1]=tmp[1]-p0[1]; dx[2]=tmp[2]-p0[2]; }
    else          { backproject(dep, fx, fy, cx, cy, P, h, WW-2, tmp);
                    dx[0]=p0[0]-tmp[0]; dx[1]=p0[1]-tmp[1]; dx[2]=p0[2]-tmp[2]; }

    if (h < HH-1) { backproject(dep, fx, fy, cx, cy, P, h+1, w, tmp);
                    dy[0]=tmp[0]-p0[0]; dy[1]=tmp[1]-p0[1]; dy[2]=tmp[2]-p0[2]; }
    else          { backproject(dep, fx, fy, cx, cy, P, HH-2, w, tmp);
                    dy[0]=p0[0]-tmp[0]; dy[1]=p0[1]-tmp[1]; dy[2]=p0[2]-tmp[2]; }

    float nx = dx[1]*dy[2] - dx[2]*dy[1];
    float ny = dx[2]*dy[0] - dx[0]*dy[2];
    float nz = dx[0]*dy[1] - dx[1]*dy[0];
    float nl = sqrtf(nx*nx + ny*ny + nz*nz) + EPSF;
    fn[0] = nx/nl; fn[1] = ny/nl; fn[2] = nz/nl;

    fpos[0]=p0[0]; fpos[1]=p0[1]; fpos[2]=p0[2];

    const float* c = rgb + (((size_t)(b*LL + s))*NN + n)*3;
    fcol[0]=c[0]; fcol[1]=c[1]; fcol[2]=c[2];

    float gx = ((float)w - cx)/fx, gy = ((float)h - cy)/fy;
    falpha = expf(-(gx*gx + gy*gy) / (2.0f*SIGMA*SIGMA));
    fvalid = d > 0.0f;
}

// ---------------------------------------------------------------------------
// Project row i (value px,py,pz, confidence conf) into frame s_next.
// Scatter-min into corr_next; record (s_next<<20)|pixel in pixdst.
// ---------------------------------------------------------------------------
__device__ __forceinline__ void project_row(
    float px, float py, float pz, float conf,
    float fx, float fy, float cx, float cy,
    const float* __restrict__ Pn,
    int b, int i, int s_next,
    int* __restrict__ corr_next, int* __restrict__ pixdst)
{
    int pix = NOPIX;
    if (conf > 0.0f) {
        float d0 = px-Pn[3], d1 = py-Pn[7], d2 = pz-Pn[11];
        float pcx = d0*Pn[0] + d1*Pn[4] + d2*Pn[8];
        float pcy = d0*Pn[1] + d1*Pn[5] + d2*Pn[9];
        float pcz = d0*Pn[2] + d1*Pn[6] + d2*Pn[10];
        if (pcz > EPSF) {
            float uf = rintf(fx*pcx/pcz + cx);   // half-to-even = jnp.round
            float vf = rintf(fy*pcy/pcz + cy);
            if (uf >= 0.0f && uf <= (float)(WW-1) &&
                vf >= 0.0f && vf <= (float)(HH-1)) {
                pix = (int)vf*WW + (int)uf;
                atomicMin(&corr_next[b*NN + pix], i);
            }
        }
    }
    pixdst[(size_t)b*MM + i] = (s_next << 20) | pix;
}

// ---------------------------------------------------------------------------
// k_init: frame-0 rows + project them into frame 1 (corr1 preset by memset),
// and reset corr2 (scatter target of step 1).
// ---------------------------------------------------------------------------
__global__ __launch_bounds__(256) void k_init(
    const float* __restrict__ rgb, const float* __restrict__ depth,
    const float* __restrict__ intr, const float* __restrict__ poses,
    float* __restrict__ map,
    int* __restrict__ corr1, int* __restrict__ corr2,
    int* __restrict__ pixdst)
{
    const int b = blockIdx.y;
    const int n = blockIdx.x*blockDim.x + threadIdx.x;
    if (n >= NN) return;

    const float* Km = intr + b*16;
    float fx = Km[0], fy = Km[5], cx = Km[2], cy = Km[6];
    const float* P1 = poses + (b*LL + 1)*16;

    float fpos[3], fn[3], fcol[3], fa; bool fv;
    frame_data(rgb, depth, intr, poses, b, 0, n, fpos, fn, fcol, fa, fv);

    float2* r2 = (float2*)(map + ((size_t)b*MM + n)*10);
    float conf = fv ? fa : 0.0f;
    if (fv) {
        r2[0] = make_float2(fpos[0], fpos[1]);
        r2[1] = make_float2(fpos[2], fn[0]);
        r2[2] = make_float2(fn[1],  fn[2]);
        r2[3] = make_float2(fcol[0], fcol[1]);
        r2[4] = make_float2(fcol[2], fa);
    } else {
        float2 z = make_float2(0.f,0.f);
        r2[0]=z; r2[1]=z; r2[2]=z; r2[3]=z; r2[4]=z;
    }
    project_row(fpos[0], fpos[1], fpos[2], conf, fx, fy, cx, cy, P1,
                b, n, 1, corr1, pixdst);
    corr2[b*NN + n] = SENTINEL;
}

// ---------------------------------------------------------------------------
// k_step (s = 1..6): fuse frame s (read corr_cur) AND project all rows
// [0,(s+1)N) into frame s+1 (scatter corr_next). Resets corr_rst.
// Thread layout per batch: t<N = pixel thread (fuse + slot + winner-row
// projection); t in [N,(s+1)N) = dedicated thread for map row t-N
// (projects the row iff it was NOT this step's winner — stable data).
// ---------------------------------------------------------------------------
__global__ __launch_bounds__(256) void k_step(
    const float* __restrict__ rgb, const float* __restrict__ depth,
    const float* __restrict__ intr, const float* __restrict__ poses,
    float* __restrict__ map,
    int* __restrict__ corr_cur, int* __restrict__ corr_next,
    int* __restrict__ corr_rst, int* __restrict__ pixdst, int s)
{
    const int b = blockIdx.y;
    const int t = blockIdx.x*blockDim.x + threadIdx.x;
    if (t >= (s+1)*NN) return;

    const float* Km = intr + b*16;
    float fx = Km[0], fy = Km[5], cx = Km[2], cy = Km[6];
    const float* Pn = poses + (b*LL + (s+1))*16;   // next frame pose

    if (t >= NN) {
        // ---- dedicated thread for map row i in [0, s*N) -------------------
        int i = t - NN;
        int e = pixdst[(size_t)b*MM + i];
        int tag = e >> 20;
        if (tag == s) {                 // not yet re-projected by a pixel thread
            int pix = e & NOPIX;
            bool winner = (pix != NOPIX) && (corr_cur[b*NN + pix] == i);
            if (!winner) {              // row untouched this step: stable read
                const float* r = map + ((size_t)b*MM + i)*10;
                float conf = r[9];
                project_row(r[0], r[1], r[2], conf, fx, fy, cx, cy, Pn,
                            b, i, s+1, corr_next, pixdst);
            }
            // winner rows: the owning pixel thread projects the final value
        }
        return;
    }

    // ---- pixel thread n -------------------------------------------------
    const int n = t;
    corr_rst[b*NN + n] = SENTINEL;      // reset third buffer (untouched else)

    float fpos[3], fn[3], fcol[3], fa; bool fv;
    frame_data(rgb, depth, intr, poses, b, s, n, fpos, fn, fcol, fa, fv);

    int cv = corr_cur[b*NN + n];
    bool match = false;
    if (cv < MM) {                      // winner row exists (cv < s*N)
        float2* c2 = (float2*)(map + ((size_t)b*MM + cv)*10);
        float2 a0 = c2[0], a1 = c2[1], a2 = c2[2], a3 = c2[3], a4 = c2[4];
        float cp0=a0.x, cp1=a0.y, cp2=a1.x;
        float cn0=a1.y, cn1=a2.x, cn2=a2.y;
        float cc0=a3.x, cc1=a3.y, cc2=a4.x;
        float cw =a4.y;

        float e0 = fpos[0]-cp0, e1 = fpos[1]-cp1, e2 = fpos[2]-cp2;
        float dist = sqrtf(e0*e0 + e1*e1 + e2*e2);
        float dotp = fn[0]*cn0 + fn[1]*cn1 + fn[2]*cn2;

        float pp0 = cp0, pp1 = cp1, pp2 = cp2, pcf = cw;  // value to project
        if (fv && dist < DIST_TH && dotp > DOT_TH) {
            match = true;
            float wgt = fa;
            float den = cw + wgt;
            float np0 = (cw*cp0 + wgt*fpos[0]) / den;
            float np1 = (cw*cp1 + wgt*fpos[1]) / den;
            float np2 = (cw*cp2 + wgt*fpos[2]) / den;
            float nc0 = (cw*cc0 + wgt*fcol[0]) / den;
            float nc1 = (cw*cc1 + wgt*fcol[1]) / den;
            float nc2 = (cw*cc2 + wgt*fcol[2]) / den;
            float nn0 = cw*cn0 + wgt*fn[0];
            float nn1 = cw*cn1 + wgt*fn[1];
            float nn2 = cw*cn2 + wgt*fn[2];
            float nl  = sqrtf(nn0*nn0 + nn1*nn1 + nn2*nn2) + EPSF;
            c2[0] = make_float2(np0, np1);
            c2[1] = make_float2(np2, nn0/nl);
            c2[2] = make_float2(nn1/nl, nn2/nl);
            c2[3] = make_float2(nc0, nc1);
            c2[4] = make_float2(nc2, den);
            pp0 = np0; pp1 = np1; pp2 = np2; pcf = den;
        }
        // project winner row's FINAL value into frame s+1 (new or old)
        project_row(pp0, pp1, pp2, pcf, fx, fy, cx, cy, Pn,
                    b, cv, s+1, corr_next, pixdst);
    }

    // ---- append slot row ------------------------------------------------
    int islot = s*NN + n;
    float2* s2 = (float2*)(map + ((size_t)b*MM + islot)*10);
    if (fv && !match) {
        s2[0] = make_float2(fpos[0], fpos[1]);
        s2[1] = make_float2(fpos[2], fn[0]);
        s2[2] = make_float2(fn[1],  fn[2]);
        s2[3] = make_float2(fcol[0], fcol[1]);
        s2[4] = make_float2(fcol[2], fa);
        project_row(fpos[0], fpos[1], fpos[2], fa, fx, fy, cx, cy, Pn,
                    b, islot, s+1, corr_next, pixdst);
    } else {
        float2 z = make_float2(0.f,0.f);
        s2[0]=z; s2[1]=z; s2[2]=z; s2[3]=z; s2[4]=z;
        pixdst[(size_t)b*MM + islot] = ((s+1) << 20) | NOPIX;
    }
}

// ---------------------------------------------------------------------------
// k_last (s = 7): fuse + append only, no projection, no resets.
// ---------------------------------------------------------------------------
__global__ __launch_bounds__(256) void k_last(
    const float* __restrict__ rgb, const float* __restrict__ depth,
    const float* __restrict__ intr, const float* __restrict__ poses,
    float* __restrict__ map, const int* __restrict__ corr_cur)
{
    const int b = blockIdx.y;
    const int n = blockIdx.x*blockDim.x + threadIdx.x;
    if (n >= NN) return;
    const int s = LL-1;

    float fpos[3], fn[3], fcol[3], fa; bool fv;
    frame_data(rgb, depth, intr, poses, b, s, n, fpos, fn, fcol, fa, fv);

    int cv = corr_cur[b*NN + n];
    bool match = false;
    if (cv < MM && fv) {
        float2* c2 = (float2*)(map + ((size_t)b*MM + cv)*10);
        float2 a0 = c2[0], a1 = c2[1], a2 = c2[2], a3 = c2[3], a4 = c2[4];
        float cp0=a0.x, cp1=a0.y, cp2=a1.x;
        float cn0=a1.y, cn1=a2.x, cn2=a2.y;
        float cc0=a3.x, cc1=a3.y, cc2=a4.x;
        float cw =a4.y;

        float e0 = fpos[0]-cp0, e1 = fpos[1]-cp1, e2 = fpos[2]-cp2;
        float dist = sqrtf(e0*e0 + e1*e1 + e2*e2);
        float dotp = fn[0]*cn0 + fn[1]*cn1 + fn[2]*cn2;

        if (dist < DIST_TH && dotp > DOT_TH) {
            match = true;
            float wgt = fa;
            float den = cw + wgt;
            float np0 = (cw*cp0 + wgt*fpos[0]) / den;
            float np1 = (cw*cp1 + wgt*fpos[1]) / den;
            float np2 = (cw*cp2 + wgt*fpos[2]) / den;
            float nc0 = (cw*cc0 + wgt*fcol[0]) / den;
            float nc1 = (cw*cc1 + wgt*fcol[1]) / den;
            float nc2 = (cw*cc2 + wgt*fcol[2]) / den;
            float nn0 = cw*cn0 + wgt*fn[0];
            float nn1 = cw*cn1 + wgt*fn[1];
            float nn2 = cw*cn2 + wgt*fn[2];
            float nl  = sqrtf(nn0*nn0 + nn1*nn1 + nn2*nn2) + EPSF;
            c2[0] = make_float2(np0, np1);
            c2[1] = make_float2(np2, nn0/nl);
            c2[2] = make_float2(nn1/nl, nn2/nl);
            c2[3] = make_float2(nc0, nc1);
            c2[4] = make_float2(nc2, den);
        }
    }

    int islot = s*NN + n;
    float2* s2 = (float2*)(map + ((size_t)b*MM + islot)*10);
    if (fv && !match) {
        s2[0] = make_float2(fpos[0], fpos[1]);
        s2[1] = make_float2(fpos[2], fn[0]);
        s2[2] = make_float2(fn[1],  fn[2]);
        s2[3] = make_float2(fcol[0], fcol[1]);
        s2[4] = make_float2(fcol[2], fa);
    } else {
        float2 z = make_float2(0.f,0.f);
        s2[0]=z; s2[1]=z; s2[2]=z; s2[3]=z; s2[4]=z;
    }
}

// ---------------------------------------------------------------------------
extern "C" void kernel_launch(void* const* d_in, const int* in_sizes, int n_in,
                              void* d_out, int out_size, void* d_ws, size_t ws_size,
                              hipStream_t stream) {
    const float* rgb   = (const float*)d_in[0];  // (B,L,H,W,3)
    const float* depth = (const float*)d_in[1];  // (B,L,H,W,1)
    const float* intr  = (const float*)d_in[2];  // (B,1,4,4)
    const float* poses = (const float*)d_in[3];  // (B,L,4,4)
    float* map = (float*)d_out;                  // (B,M,10)

    // d_ws layout: 3 corr buffers (B*N ints each) + pixdst (B*M ints) = 6.8 MB
    int* corr   = (int*)d_ws;
    int* pixdst = corr + 3*BB*NN;

    // preset corr buffer 1 (k_init's scatter target)
    hipMemsetAsync(corr + 1*BB*NN, 0x7F, (size_t)BB*NN*sizeof(int), stream);

    dim3 blk(256);
    k_init<<<dim3((NN+255)/256, BB), blk, 0, stream>>>(
        rgb, depth, intr, poses, map,
        corr + 1*BB*NN, corr + 2*BB*NN, pixdst);

    for (int s = 1; s <= 6; ++s) {
        int* cur = corr + (s      % 3)*BB*NN;
        int* nxt = corr + ((s+1)  % 3)*BB*NN;
        int* rst = corr + ((s+2)  % 3)*BB*NN;
        k_step<<<dim3(((s+1)*NN + 255)/256, BB), blk, 0, stream>>>(
            rgb, depth, intr, poses, map, cur, nxt, rst, pixdst, s);
    }

    k_last<<<dim3((NN+255)/256, BB), blk, 0, stream>>>(
        rgb, depth, intr, poses, map, corr + (7 % 3)*BB*NN);
}

// Round 7
// 158.340 us; speedup vs baseline: 6.2731x; 1.0022x over previous
//
#include <hip/hip_runtime.h>
#include <math.h>

#define BB 2
#define LL 8
#define HH 240
#define WW 320
#define NN (HH*WW)      // 76800
#define MM (LL*NN)      // 614400

#define DIST_TH 0.05f
#define DOT_TH  0.9396926207859084f   // cos(20 deg)
#define SIGMA   0.6f
#define EPSF    1e-8f
#define SENTINEL 0x7F7F7F7F
#define NOPIX   0xFFFFF

// ---------------------------------------------------------------------------
__device__ __forceinline__ float backproject(
    const float* __restrict__ dep,
    float fx, float fy, float cx, float cy,
    const float* __restrict__ P,
    int h, int w, float o[3])
{
    float d  = dep[h*WW + w];
    float gx = ((float)w - cx) / fx;
    float gy = ((float)h - cy) / fy;
    float px = gx*d, py = gy*d, pz = d;
    o[0] = P[0]*px + P[1]*py + P[2]*pz  + P[3];
    o[1] = P[4]*px + P[5]*py + P[6]*pz  + P[7];
    o[2] = P[8]*px + P[9]*py + P[10]*pz + P[11];
    return d;
}

__device__ __forceinline__ void frame_data(
    const float* __restrict__ rgb, const float* __restrict__ depth,
    const float* __restrict__ intr, const float* __restrict__ poses,
    int b, int s, int n,
    float fpos[3], float fn[3], float fcol[3], float& falpha, bool& fvalid)
{
    const float* Km = intr + b*16;
    float fx = Km[0], fy = Km[5], cx = Km[2], cy = Km[6];
    const float* P  = poses + (b*LL + s)*16;
    const float* dep = depth + ((size_t)(b*LL + s))*NN;

    int h = n / WW, w = n % WW;

    float p0[3], tmp[3], dx[3], dy[3];
    float d = backproject(dep, fx, fy, cx, cy, P, h, w, p0);

    if (w < WW-1) { backproject(dep, fx, fy, cx, cy, P, h, w+1, tmp);
                    dx[0]=tmp[0]-p0[0]; dx[1]=tmp[1]-p0[1]; dx[2]=tmp[2]-p0[2]; }
    else          { backproject(dep, fx, fy, cx, cy, P, h, WW-2, tmp);
                    dx[0]=p0[0]-tmp[0]; dx[1]=p0[1]-tmp[1]; dx[2]=p0[2]-tmp[2]; }

    if (h < HH-1) { backproject(dep, fx, fy, cx, cy, P, h+1, w, tmp);
                    dy[0]=tmp[0]-p0[0]; dy[1]=tmp[1]-p0[1]; dy[2]=tmp[2]-p0[2]; }
    else          { backproject(dep, fx, fy, cx, cy, P, HH-2, w, tmp);
                    dy[0]=p0[0]-tmp[0]; dy[1]=p0[1]-tmp[1]; dy[2]=p0[2]-tmp[2]; }

    float nx = dx[1]*dy[2] - dx[2]*dy[1];
    float ny = dx[2]*dy[0] - dx[0]*dy[2];
    float nz = dx[0]*dy[1] - dx[1]*dy[0];
    float nl = sqrtf(nx*nx + ny*ny + nz*nz) + EPSF;
    fn[0] = nx/nl; fn[1] = ny/nl; fn[2] = nz/nl;

    fpos[0]=p0[0]; fpos[1]=p0[1]; fpos[2]=p0[2];

    const float* c = rgb + (((size_t)(b*LL + s))*NN + n)*3;
    fcol[0]=c[0]; fcol[1]=c[1]; fcol[2]=c[2];

    float gx = ((float)w - cx)/fx, gy = ((float)h - cy)/fy;
    falpha = expf(-(gx*gx + gy*gy) / (2.0f*SIGMA*SIGMA));
    fvalid = d > 0.0f;
}

// ---------------------------------------------------------------------------
// Project row i (value px,py,pz, confidence conf) into frame s_next.
// Scatter-min into corr_next; record (s_next<<20)|pixel in pixdst.
// ---------------------------------------------------------------------------
__device__ __forceinline__ void project_row(
    float px, float py, float pz, float conf,
    float fx, float fy, float cx, float cy,
    const float* __restrict__ Pn,
    int b, int i, int s_next,
    int* __restrict__ corr_next, int* __restrict__ pixdst)
{
    int pix = NOPIX;
    if (conf > 0.0f) {
        float d0 = px-Pn[3], d1 = py-Pn[7], d2 = pz-Pn[11];
        float pcx = d0*Pn[0] + d1*Pn[4] + d2*Pn[8];
        float pcy = d0*Pn[1] + d1*Pn[5] + d2*Pn[9];
        float pcz = d0*Pn[2] + d1*Pn[6] + d2*Pn[10];
        if (pcz > EPSF) {
            float uf = rintf(fx*pcx/pcz + cx);   // half-to-even = jnp.round
            float vf = rintf(fy*pcy/pcz + cy);
            if (uf >= 0.0f && uf <= (float)(WW-1) &&
                vf >= 0.0f && vf <= (float)(HH-1)) {
                pix = (int)vf*WW + (int)uf;
                atomicMin(&corr_next[b*NN + pix], i);
            }
        }
    }
    pixdst[(size_t)b*MM + i] = (s_next << 20) | pix;
}

// ---------------------------------------------------------------------------
// k_reset: fast sentinel fill of corr buffer 1 (hipMemsetAsync's fill kernel
// measured 42 us for 600 KB — this does it coalesced int4 in ~3 us).
// ---------------------------------------------------------------------------
__global__ __launch_bounds__(256) void k_reset(int4* __restrict__ c1)
{
    int t = blockIdx.x*blockDim.x + threadIdx.x;   // BB*NN/4 = 38400 int4s
    if (t < BB*NN/4)
        c1[t] = make_int4(SENTINEL, SENTINEL, SENTINEL, SENTINEL);
}

// ---------------------------------------------------------------------------
// k_init: frame-0 rows + project them into frame 1 (corr1 preset by k_reset),
// and reset corr2 (scatter target of step 1).
// ---------------------------------------------------------------------------
__global__ __launch_bounds__(256) void k_init(
    const float* __restrict__ rgb, const float* __restrict__ depth,
    const float* __restrict__ intr, const float* __restrict__ poses,
    float* __restrict__ map,
    int* __restrict__ corr1, int* __restrict__ corr2,
    int* __restrict__ pixdst)
{
    const int b = blockIdx.y;
    const int n = blockIdx.x*blockDim.x + threadIdx.x;
    if (n >= NN) return;

    const float* Km = intr + b*16;
    float fx = Km[0], fy = Km[5], cx = Km[2], cy = Km[6];
    const float* P1 = poses + (b*LL + 1)*16;

    float fpos[3], fn[3], fcol[3], fa; bool fv;
    frame_data(rgb, depth, intr, poses, b, 0, n, fpos, fn, fcol, fa, fv);

    float2* r2 = (float2*)(map + ((size_t)b*MM + n)*10);
    float conf = fv ? fa : 0.0f;
    if (fv) {
        r2[0] = make_float2(fpos[0], fpos[1]);
        r2[1] = make_float2(fpos[2], fn[0]);
        r2[2] = make_float2(fn[1],  fn[2]);
        r2[3] = make_float2(fcol[0], fcol[1]);
        r2[4] = make_float2(fcol[2], fa);
    } else {
        float2 z = make_float2(0.f,0.f);
        r2[0]=z; r2[1]=z; r2[2]=z; r2[3]=z; r2[4]=z;
    }
    project_row(fpos[0], fpos[1], fpos[2], conf, fx, fy, cx, cy, P1,
                b, n, 1, corr1, pixdst);
    corr2[b*NN + n] = SENTINEL;
}

// ---------------------------------------------------------------------------
// k_step (s = 1..6): fuse frame s (read corr_cur) AND project all rows
// [0,(s+1)N) into frame s+1 (scatter corr_next). Resets corr_rst.
// Thread layout per batch: t<N = pixel thread (fuse + slot + winner-row
// projection); t in [N,(s+1)N) = dedicated thread for map row t-N
// (projects the row iff it was NOT this step's winner — stable data).
// ---------------------------------------------------------------------------
__global__ __launch_bounds__(256) void k_step(
    const float* __restrict__ rgb, const float* __restrict__ depth,
    const float* __restrict__ intr, const float* __restrict__ poses,
    float* __restrict__ map,
    int* __restrict__ corr_cur, int* __restrict__ corr_next,
    int* __restrict__ corr_rst, int* __restrict__ pixdst, int s)
{
    const int b = blockIdx.y;
    const int t = blockIdx.x*blockDim.x + threadIdx.x;
    if (t >= (s+1)*NN) return;

    const float* Km = intr + b*16;
    float fx = Km[0], fy = Km[5], cx = Km[2], cy = Km[6];
    const float* Pn = poses + (b*LL + (s+1))*16;   // next frame pose

    if (t >= NN) {
        // ---- dedicated thread for map row i in [0, s*N) -------------------
        int i = t - NN;
        int e = pixdst[(size_t)b*MM + i];
        int tag = e >> 20;
        if (tag == s) {                 // not yet re-projected by a pixel thread
            int pix = e & NOPIX;
            bool winner = (pix != NOPIX) && (corr_cur[b*NN + pix] == i);
            if (!winner) {              // row untouched this step: stable read
                const float* r = map + ((size_t)b*MM + i)*10;
                float conf = r[9];
                project_row(r[0], r[1], r[2], conf, fx, fy, cx, cy, Pn,
                            b, i, s+1, corr_next, pixdst);
            }
            // winner rows: the owning pixel thread projects the final value
        }
        return;
    }

    // ---- pixel thread n -------------------------------------------------
    const int n = t;
    corr_rst[b*NN + n] = SENTINEL;      // reset third buffer (untouched else)

    float fpos[3], fn[3], fcol[3], fa; bool fv;
    frame_data(rgb, depth, intr, poses, b, s, n, fpos, fn, fcol, fa, fv);

    int cv = corr_cur[b*NN + n];
    bool match = false;
    if (cv < MM) {                      // winner row exists (cv < s*N)
        float2* c2 = (float2*)(map + ((size_t)b*MM + cv)*10);
        float2 a0 = c2[0], a1 = c2[1], a2 = c2[2], a3 = c2[3], a4 = c2[4];
        float cp0=a0.x, cp1=a0.y, cp2=a1.x;
        float cn0=a1.y, cn1=a2.x, cn2=a2.y;
        float cc0=a3.x, cc1=a3.y, cc2=a4.x;
        float cw =a4.y;

        float e0 = fpos[0]-cp0, e1 = fpos[1]-cp1, e2 = fpos[2]-cp2;
        float dist = sqrtf(e0*e0 + e1*e1 + e2*e2);
        float dotp = fn[0]*cn0 + fn[1]*cn1 + fn[2]*cn2;

        float pp0 = cp0, pp1 = cp1, pp2 = cp2, pcf = cw;  // value to project
        if (fv && dist < DIST_TH && dotp > DOT_TH) {
            match = true;
            float wgt = fa;
            float den = cw + wgt;
            float np0 = (cw*cp0 + wgt*fpos[0]) / den;
            float np1 = (cw*cp1 + wgt*fpos[1]) / den;
            float np2 = (cw*cp2 + wgt*fpos[2]) / den;
            float nc0 = (cw*cc0 + wgt*fcol[0]) / den;
            float nc1 = (cw*cc1 + wgt*fcol[1]) / den;
            float nc2 = (cw*cc2 + wgt*fcol[2]) / den;
            float nn0 = cw*cn0 + wgt*fn[0];
            float nn1 = cw*cn1 + wgt*fn[1];
            float nn2 = cw*cn2 + wgt*fn[2];
            float nl  = sqrtf(nn0*nn0 + nn1*nn1 + nn2*nn2) + EPSF;
            c2[0] = make_float2(np0, np1);
            c2[1] = make_float2(np2, nn0/nl);
            c2[2] = make_float2(nn1/nl, nn2/nl);
            c2[3] = make_float2(nc0, nc1);
            c2[4] = make_float2(nc2, den);
            pp0 = np0; pp1 = np1; pp2 = np2; pcf = den;
        }
        // project winner row's FINAL value into frame s+1 (new or old)
        project_row(pp0, pp1, pp2, pcf, fx, fy, cx, cy, Pn,
                    b, cv, s+1, corr_next, pixdst);
    }

    // ---- append slot row ------------------------------------------------
    int islot = s*NN + n;
    float2* s2 = (float2*)(map + ((size_t)b*MM + islot)*10);
    if (fv && !match) {
        s2[0] = make_float2(fpos[0], fpos[1]);
        s2[1] = make_float2(fpos[2], fn[0]);
        s2[2] = make_float2(fn[1],  fn[2]);
        s2[3] = make_float2(fcol[0], fcol[1]);
        s2[4] = make_float2(fcol[2], fa);
        project_row(fpos[0], fpos[1], fpos[2], fa, fx, fy, cx, cy, Pn,
                    b, islot, s+1, corr_next, pixdst);
    } else {
        float2 z = make_float2(0.f,0.f);
        s2[0]=z; s2[1]=z; s2[2]=z; s2[3]=z; s2[4]=z;
        pixdst[(size_t)b*MM + islot] = ((s+1) << 20) | NOPIX;
    }
}

// ---------------------------------------------------------------------------
// k_last (s = 7): fuse + append only, no projection, no resets.
// ---------------------------------------------------------------------------
__global__ __launch_bounds__(256) void k_last(
    const float* __restrict__ rgb, const float* __restrict__ depth,
    const float* __restrict__ intr, const float* __restrict__ poses,
    float* __restrict__ map, const int* __restrict__ corr_cur)
{
    const int b = blockIdx.y;
    const int n = blockIdx.x*blockDim.x + threadIdx.x;
    if (n >= NN) return;
    const int s = LL-1;

    float fpos[3], fn[3], fcol[3], fa; bool fv;
    frame_data(rgb, depth, intr, poses, b, s, n, fpos, fn, fcol, fa, fv);

    int cv = corr_cur[b*NN + n];
    bool match = false;
    if (cv < MM && fv) {
        float2* c2 = (float2*)(map + ((size_t)b*MM + cv)*10);
        float2 a0 = c2[0], a1 = c2[1], a2 = c2[2], a3 = c2[3], a4 = c2[4];
        float cp0=a0.x, cp1=a0.y, cp2=a1.x;
        float cn0=a1.y, cn1=a2.x, cn2=a2.y;
        float cc0=a3.x, cc1=a3.y, cc2=a4.x;
        float cw =a4.y;

        float e0 = fpos[0]-cp0, e1 = fpos[1]-cp1, e2 = fpos[2]-cp2;
        float dist = sqrtf(e0*e0 + e1*e1 + e2*e2);
        float dotp = fn[0]*cn0 + fn[1]*cn1 + fn[2]*cn2;

        if (dist < DIST_TH && dotp > DOT_TH) {
            match = true;
            float wgt = fa;
            float den = cw + wgt;
            float np0 = (cw*cp0 + wgt*fpos[0]) / den;
            float np1 = (cw*cp1 + wgt*fpos[1]) / den;
            float np2 = (cw*cp2 + wgt*fpos[2]) / den;
            float nc0 = (cw*cc0 + wgt*fcol[0]) / den;
            float nc1 = (cw*cc1 + wgt*fcol[1]) / den;
            float nc2 = (cw*cc2 + wgt*fcol[2]) / den;
            float nn0 = cw*cn0 + wgt*fn[0];
            float nn1 = cw*cn1 + wgt*fn[1];
            float nn2 = cw*cn2 + wgt*fn[2];
            float nl  = sqrtf(nn0*nn0 + nn1*nn1 + nn2*nn2) + EPSF;
            c2[0] = make_float2(np0, np1);
            c2[1] = make_float2(np2, nn0/nl);
            c2[2] = make_float2(nn1/nl, nn2/nl);
            c2[3] = make_float2(nc0, nc1);
            c2[4] = make_float2(nc2, den);
        }
    }

    int islot = s*NN + n;
    float2* s2 = (float2*)(map + ((size_t)b*MM + islot)*10);
    if (fv && !match) {
        s2[0] = make_float2(fpos[0], fpos[1]);
        s2[1] = make_float2(fpos[2], fn[0]);
        s2[2] = make_float2(fn[1],  fn[2]);
        s2[3] = make_float2(fcol[0], fcol[1]);
        s2[4] = make_float2(fcol[2], fa);
    } else {
        float2 z = make_float2(0.f,0.f);
        s2[0]=z; s2[1]=z; s2[2]=z; s2[3]=z; s2[4]=z;
    }
}

// ---------------------------------------------------------------------------
extern "C" void kernel_launch(void* const* d_in, const int* in_sizes, int n_in,
                              void* d_out, int out_size, void* d_ws, size_t ws_size,
                              hipStream_t stream) {
    const float* rgb   = (const float*)d_in[0];  // (B,L,H,W,3)
    const float* depth = (const float*)d_in[1];  // (B,L,H,W,1)
    const float* intr  = (const float*)d_in[2];  // (B,1,4,4)
    const float* poses = (const float*)d_in[3];  // (B,L,4,4)
    float* map = (float*)d_out;                  // (B,M,10)

    // d_ws layout: 3 corr buffers (B*N ints each) + pixdst (B*M ints) = 6.8 MB
    int* corr   = (int*)d_ws;
    int* pixdst = corr + 3*BB*NN;

    dim3 blk(256);

    // preset corr buffer 1 (k_init's scatter target) — custom fast fill
    k_reset<<<dim3((BB*NN/4 + 255)/256), blk, 0, stream>>>(
        (int4*)(corr + 1*BB*NN));

    k_init<<<dim3((NN+255)/256, BB), blk, 0, stream>>>(
        rgb, depth, intr, poses, map,
        corr + 1*BB*NN, corr + 2*BB*NN, pixdst);

    for (int s = 1; s <= 6; ++s) {
        int* cur = corr + (s      % 3)*BB*NN;
        int* nxt = corr + ((s+1)  % 3)*BB*NN;
        int* rst = corr + ((s+2)  % 3)*BB*NN;
        k_step<<<dim3(((s+1)*NN + 255)/256, BB), blk, 0, stream>>>(
            rgb, depth, intr, poses, map, cur, nxt, rst, pixdst, s);
    }

    k_last<<<dim3((NN+255)/256, BB), blk, 0, stream>>>(
        rgb, depth, intr, poses, map, corr + (7 % 3)*BB*NN);
}

// Round 8
// 152.895 us; speedup vs baseline: 6.4965x; 1.0356x over previous
//
#include <hip/hip_runtime.h>
#include <math.h>

#define BB 2
#define LL 8
#define HH 240
#define WW 320
#define NN (HH*WW)      // 76800
#define MM (LL*NN)      // 614400

#define DIST_TH 0.05f
#define DOT_TH  0.9396926207859084f   // cos(20 deg)
#define SIGMA   0.6f
#define EPSF    1e-8f
#define SENTINEL 0x7F7F7F7F
#define NOPIX   0xFFFFF

// ---------------------------------------------------------------------------
__device__ __forceinline__ float backproject(
    const float* __restrict__ dep,
    float fx, float fy, float cx, float cy,
    const float* __restrict__ P,
    int h, int w, float o[3])
{
    float d  = dep[h*WW + w];
    float gx = ((float)w - cx) / fx;
    float gy = ((float)h - cy) / fy;
    float px = gx*d, py = gy*d, pz = d;
    o[0] = P[0]*px + P[1]*py + P[2]*pz  + P[3];
    o[1] = P[4]*px + P[5]*py + P[6]*pz  + P[7];
    o[2] = P[8]*px + P[9]*py + P[10]*pz + P[11];
    return d;
}

__device__ __forceinline__ void frame_data(
    const float* __restrict__ rgb, const float* __restrict__ depth,
    const float* __restrict__ intr, const float* __restrict__ poses,
    int b, int s, int n,
    float fpos[3], float fn[3], float fcol[3], float& falpha, bool& fvalid)
{
    const float* Km = intr + b*16;
    float fx = Km[0], fy = Km[5], cx = Km[2], cy = Km[6];
    const float* P  = poses + (b*LL + s)*16;
    const float* dep = depth + ((size_t)(b*LL + s))*NN;

    int h = n / WW, w = n % WW;

    float p0[3], tmp[3], dx[3], dy[3];
    float d = backproject(dep, fx, fy, cx, cy, P, h, w, p0);

    if (w < WW-1) { backproject(dep, fx, fy, cx, cy, P, h, w+1, tmp);
                    dx[0]=tmp[0]-p0[0]; dx[1]=tmp[1]-p0[1]; dx[2]=tmp[2]-p0[2]; }
    else          { backproject(dep, fx, fy, cx, cy, P, h, WW-2, tmp);
                    dx[0]=p0[0]-tmp[0]; dx[1]=p0[1]-tmp[1]; dx[2]=p0[2]-tmp[2]; }

    if (h < HH-1) { backproject(dep, fx, fy, cx, cy, P, h+1, w, tmp);
                    dy[0]=tmp[0]-p0[0]; dy[1]=tmp[1]-p0[1]; dy[2]=tmp[2]-p0[2]; }
    else          { backproject(dep, fx, fy, cx, cy, P, HH-2, w, tmp);
                    dy[0]=p0[0]-tmp[0]; dy[1]=p0[1]-tmp[1]; dy[2]=p0[2]-tmp[2]; }

    float nx = dx[1]*dy[2] - dx[2]*dy[1];
    float ny = dx[2]*dy[0] - dx[0]*dy[2];
    float nz = dx[0]*dy[1] - dx[1]*dy[0];
    float nl = sqrtf(nx*nx + ny*ny + nz*nz) + EPSF;
    fn[0] = nx/nl; fn[1] = ny/nl; fn[2] = nz/nl;

    fpos[0]=p0[0]; fpos[1]=p0[1]; fpos[2]=p0[2];

    const float* c = rgb + (((size_t)(b*LL + s))*NN + n)*3;
    fcol[0]=c[0]; fcol[1]=c[1]; fcol[2]=c[2];

    float gx = ((float)w - cx)/fx, gy = ((float)h - cy)/fy;
    falpha = expf(-(gx*gx + gy*gy) / (2.0f*SIGMA*SIGMA));
    fvalid = d > 0.0f;
}

// ---------------------------------------------------------------------------
// Project row i (value px,py,pz, confidence conf) into frame s_next.
// Scatter-min into corr_next; record (s_next<<20)|pixel in pixdst.
// ---------------------------------------------------------------------------
__device__ __forceinline__ void project_row(
    float px, float py, float pz, float conf,
    float fx, float fy, float cx, float cy,
    const float* __restrict__ Pn,
    int b, int i, int s_next,
    int* __restrict__ corr_next, int* __restrict__ pixdst)
{
    int pix = NOPIX;
    if (conf > 0.0f) {
        float d0 = px-Pn[3], d1 = py-Pn[7], d2 = pz-Pn[11];
        float pcx = d0*Pn[0] + d1*Pn[4] + d2*Pn[8];
        float pcy = d0*Pn[1] + d1*Pn[5] + d2*Pn[9];
        float pcz = d0*Pn[2] + d1*Pn[6] + d2*Pn[10];
        if (pcz > EPSF) {
            float uf = rintf(fx*pcx/pcz + cx);   // half-to-even = jnp.round
            float vf = rintf(fy*pcy/pcz + cy);
            if (uf >= 0.0f && uf <= (float)(WW-1) &&
                vf >= 0.0f && vf <= (float)(HH-1)) {
                pix = (int)vf*WW + (int)uf;
                atomicMin(&corr_next[b*NN + pix], i);
            }
        }
    }
    pixdst[(size_t)b*MM + i] = (s_next << 20) | pix;
}

// ---------------------------------------------------------------------------
// k_reset: sentinel fill of corr buffer 1 (k_init's scatter target).
// ---------------------------------------------------------------------------
__global__ __launch_bounds__(256) void k_reset(int4* __restrict__ c1)
{
    int t = blockIdx.x*blockDim.x + threadIdx.x;   // BB*NN/4 = 38400 int4s
    if (t < BB*NN/4)
        c1[t] = make_int4(SENTINEL, SENTINEL, SENTINEL, SENTINEL);
}

// ---------------------------------------------------------------------------
// k_init: frame-0 rows + posconf mirror + project into frame 1; reset corr2.
// ---------------------------------------------------------------------------
__global__ __launch_bounds__(256) void k_init(
    const float* __restrict__ rgb, const float* __restrict__ depth,
    const float* __restrict__ intr, const float* __restrict__ poses,
    float* __restrict__ map, float4* __restrict__ posconf,
    int* __restrict__ corr1, int* __restrict__ corr2,
    int* __restrict__ pixdst)
{
    const int b = blockIdx.y;
    const int n = blockIdx.x*blockDim.x + threadIdx.x;
    if (n >= NN) return;

    const float* Km = intr + b*16;
    float fx = Km[0], fy = Km[5], cx = Km[2], cy = Km[6];
    const float* P1 = poses + (b*LL + 1)*16;

    float fpos[3], fn[3], fcol[3], fa; bool fv;
    frame_data(rgb, depth, intr, poses, b, 0, n, fpos, fn, fcol, fa, fv);

    float2* r2 = (float2*)(map + ((size_t)b*MM + n)*10);
    float conf = fv ? fa : 0.0f;
    if (fv) {
        r2[0] = make_float2(fpos[0], fpos[1]);
        r2[1] = make_float2(fpos[2], fn[0]);
        r2[2] = make_float2(fn[1],  fn[2]);
        r2[3] = make_float2(fcol[0], fcol[1]);
        r2[4] = make_float2(fcol[2], fa);
        posconf[(size_t)b*MM + n] = make_float4(fpos[0], fpos[1], fpos[2], fa);
    } else {
        float2 z = make_float2(0.f,0.f);
        r2[0]=z; r2[1]=z; r2[2]=z; r2[3]=z; r2[4]=z;
        posconf[(size_t)b*MM + n] = make_float4(0.f,0.f,0.f,0.f);
    }
    project_row(fpos[0], fpos[1], fpos[2], conf, fx, fy, cx, cy, P1,
                b, n, 1, corr1, pixdst);
    corr2[b*NN + n] = SENTINEL;
}

// ---------------------------------------------------------------------------
// k_step (s = 1..6): fuse frame s (read corr_cur) AND project all rows
// [0,(s+1)N) into frame s+1 (scatter corr_next). Resets corr_rst.
// t<N: pixel thread (fuse + append + winner-row projection).
// t in [N,(s+1)N): dedicated thread for map row t-N — projects the row iff
// it was NOT this step's winner, reading the compact posconf mirror
// (coalesced 16B) instead of the 40B map row.
// ---------------------------------------------------------------------------
__global__ __launch_bounds__(256) void k_step(
    const float* __restrict__ rgb, const float* __restrict__ depth,
    const float* __restrict__ intr, const float* __restrict__ poses,
    float* __restrict__ map, float4* __restrict__ posconf,
    int* __restrict__ corr_cur, int* __restrict__ corr_next,
    int* __restrict__ corr_rst, int* __restrict__ pixdst, int s)
{
    const int b = blockIdx.y;
    const int t = blockIdx.x*blockDim.x + threadIdx.x;
    if (t >= (s+1)*NN) return;

    const float* Km = intr + b*16;
    float fx = Km[0], fy = Km[5], cx = Km[2], cy = Km[6];
    const float* Pn = poses + (b*LL + (s+1))*16;   // next frame pose

    if (t >= NN) {
        // ---- dedicated thread for map row i in [0, s*N) -------------------
        int i = t - NN;
        int e = pixdst[(size_t)b*MM + i];
        int tag = e >> 20;
        if (tag == s) {                 // not yet re-projected by a pixel thread
            int pix = e & NOPIX;
            bool winner = (pix != NOPIX) && (corr_cur[b*NN + pix] == i);
            if (!winner) {              // row untouched this step: stable read
                float4 pc = posconf[(size_t)b*MM + i];
                project_row(pc.x, pc.y, pc.z, pc.w, fx, fy, cx, cy, Pn,
                            b, i, s+1, corr_next, pixdst);
            }
            // winner rows: the owning pixel thread projects the final value
        }
        return;
    }

    // ---- pixel thread n -------------------------------------------------
    const int n = t;
    corr_rst[b*NN + n] = SENTINEL;      // reset third buffer (untouched else)

    float fpos[3], fn[3], fcol[3], fa; bool fv;
    frame_data(rgb, depth, intr, poses, b, s, n, fpos, fn, fcol, fa, fv);

    int cv = corr_cur[b*NN + n];
    bool match = false;
    if (cv < MM) {                      // winner row exists (cv < s*N)
        float2* c2 = (float2*)(map + ((size_t)b*MM + cv)*10);
        float2 a0 = c2[0], a1 = c2[1], a2 = c2[2], a3 = c2[3], a4 = c2[4];
        float cp0=a0.x, cp1=a0.y, cp2=a1.x;
        float cn0=a1.y, cn1=a2.x, cn2=a2.y;
        float cc0=a3.x, cc1=a3.y, cc2=a4.x;
        float cw =a4.y;

        float e0 = fpos[0]-cp0, e1 = fpos[1]-cp1, e2 = fpos[2]-cp2;
        float dist = sqrtf(e0*e0 + e1*e1 + e2*e2);
        float dotp = fn[0]*cn0 + fn[1]*cn1 + fn[2]*cn2;

        float pp0 = cp0, pp1 = cp1, pp2 = cp2, pcf = cw;  // value to project
        if (fv && dist < DIST_TH && dotp > DOT_TH) {
            match = true;
            float wgt = fa;
            float den = cw + wgt;
            float np0 = (cw*cp0 + wgt*fpos[0]) / den;
            float np1 = (cw*cp1 + wgt*fpos[1]) / den;
            float np2 = (cw*cp2 + wgt*fpos[2]) / den;
            float nc0 = (cw*cc0 + wgt*fcol[0]) / den;
            float nc1 = (cw*cc1 + wgt*fcol[1]) / den;
            float nc2 = (cw*cc2 + wgt*fcol[2]) / den;
            float nn0 = cw*cn0 + wgt*fn[0];
            float nn1 = cw*cn1 + wgt*fn[1];
            float nn2 = cw*cn2 + wgt*fn[2];
            float nl  = sqrtf(nn0*nn0 + nn1*nn1 + nn2*nn2) + EPSF;
            c2[0] = make_float2(np0, np1);
            c2[1] = make_float2(np2, nn0/nl);
            c2[2] = make_float2(nn1/nl, nn2/nl);
            c2[3] = make_float2(nc0, nc1);
            c2[4] = make_float2(nc2, den);
            posconf[(size_t)b*MM + cv] = make_float4(np0, np1, np2, den);
            pp0 = np0; pp1 = np1; pp2 = np2; pcf = den;
        }
        // project winner row's FINAL value into frame s+1 (new or old)
        project_row(pp0, pp1, pp2, pcf, fx, fy, cx, cy, Pn,
                    b, cv, s+1, corr_next, pixdst);
    }

    // ---- append slot row ------------------------------------------------
    int islot = s*NN + n;
    float2* s2 = (float2*)(map + ((size_t)b*MM + islot)*10);
    if (fv && !match) {
        s2[0] = make_float2(fpos[0], fpos[1]);
        s2[1] = make_float2(fpos[2], fn[0]);
        s2[2] = make_float2(fn[1],  fn[2]);
        s2[3] = make_float2(fcol[0], fcol[1]);
        s2[4] = make_float2(fcol[2], fa);
        posconf[(size_t)b*MM + islot] = make_float4(fpos[0], fpos[1], fpos[2], fa);
        project_row(fpos[0], fpos[1], fpos[2], fa, fx, fy, cx, cy, Pn,
                    b, islot, s+1, corr_next, pixdst);
    } else {
        float2 z = make_float2(0.f,0.f);
        s2[0]=z; s2[1]=z; s2[2]=z; s2[3]=z; s2[4]=z;
        posconf[(size_t)b*MM + islot] = make_float4(0.f,0.f,0.f,0.f);
        pixdst[(size_t)b*MM + islot] = ((s+1) << 20) | NOPIX;
    }
}

// ---------------------------------------------------------------------------
// k_last (s = 7): fuse + append only, no projection, no resets.
// ---------------------------------------------------------------------------
__global__ __launch_bounds__(256) void k_last(
    const float* __restrict__ rgb, const float* __restrict__ depth,
    const float* __restrict__ intr, const float* __restrict__ poses,
    float* __restrict__ map, const int* __restrict__ corr_cur)
{
    const int b = blockIdx.y;
    const int n = blockIdx.x*blockDim.x + threadIdx.x;
    if (n >= NN) return;
    const int s = LL-1;

    float fpos[3], fn[3], fcol[3], fa; bool fv;
    frame_data(rgb, depth, intr, poses, b, s, n, fpos, fn, fcol, fa, fv);

    int cv = corr_cur[b*NN + n];
    bool match = false;
    if (cv < MM && fv) {
        float2* c2 = (float2*)(map + ((size_t)b*MM + cv)*10);
        float2 a0 = c2[0], a1 = c2[1], a2 = c2[2], a3 = c2[3], a4 = c2[4];
        float cp0=a0.x, cp1=a0.y, cp2=a1.x;
        float cn0=a1.y, cn1=a2.x, cn2=a2.y;
        float cc0=a3.x, cc1=a3.y, cc2=a4.x;
        float cw =a4.y;

        float e0 = fpos[0]-cp0, e1 = fpos[1]-cp1, e2 = fpos[2]-cp2;
        float dist = sqrtf(e0*e0 + e1*e1 + e2*e2);
        float dotp = fn[0]*cn0 + fn[1]*cn1 + fn[2]*cn2;

        if (dist < DIST_TH && dotp > DOT_TH) {
            match = true;
            float wgt = fa;
            float den = cw + wgt;
            float np0 = (cw*cp0 + wgt*fpos[0]) / den;
            float np1 = (cw*cp1 + wgt*fpos[1]) / den;
            float np2 = (cw*cp2 + wgt*fpos[2]) / den;
            float nc0 = (cw*cc0 + wgt*fcol[0]) / den;
            float nc1 = (cw*cc1 + wgt*fcol[1]) / den;
            float nc2 = (cw*cc2 + wgt*fcol[2]) / den;
            float nn0 = cw*cn0 + wgt*fn[0];
            float nn1 = cw*cn1 + wgt*fn[1];
            float nn2 = cw*cn2 + wgt*fn[2];
            float nl  = sqrtf(nn0*nn0 + nn1*nn1 + nn2*nn2) + EPSF;
            c2[0] = make_float2(np0, np1);
            c2[1] = make_float2(np2, nn0/nl);
            c2[2] = make_float2(nn1/nl, nn2/nl);
            c2[3] = make_float2(nc0, nc1);
            c2[4] = make_float2(nc2, den);
        }
    }

    int islot = s*NN + n;
    float2* s2 = (float2*)(map + ((size_t)b*MM + islot)*10);
    if (fv && !match) {
        s2[0] = make_float2(fpos[0], fpos[1]);
        s2[1] = make_float2(fpos[2], fn[0]);
        s2[2] = make_float2(fn[1],  fn[2]);
        s2[3] = make_float2(fcol[0], fcol[1]);
        s2[4] = make_float2(fcol[2], fa);
    } else {
        float2 z = make_float2(0.f,0.f);
        s2[0]=z; s2[1]=z; s2[2]=z; s2[3]=z; s2[4]=z;
    }
}

// ---------------------------------------------------------------------------
extern "C" void kernel_launch(void* const* d_in, const int* in_sizes, int n_in,
                              void* d_out, int out_size, void* d_ws, size_t ws_size,
                              hipStream_t stream) {
    const float* rgb   = (const float*)d_in[0];  // (B,L,H,W,3)
    const float* depth = (const float*)d_in[1];  // (B,L,H,W,1)
    const float* intr  = (const float*)d_in[2];  // (B,1,4,4)
    const float* poses = (const float*)d_in[3];  // (B,L,4,4)
    float* map = (float*)d_out;                  // (B,M,10)

    // d_ws: 3 corr buffers (B*N ints) + pixdst (B*M ints) + posconf (B*M f4)
    int*    corr    = (int*)d_ws;
    int*    pixdst  = corr + 3*BB*NN;
    float4* posconf = (float4*)(pixdst + BB*MM);

    dim3 blk(256);

    // preset corr buffer 1 (k_init's scatter target)
    k_reset<<<dim3((BB*NN/4 + 255)/256), blk, 0, stream>>>(
        (int4*)(corr + 1*BB*NN));

    k_init<<<dim3((NN+255)/256, BB), blk, 0, stream>>>(
        rgb, depth, intr, poses, map, posconf,
        corr + 1*BB*NN, corr + 2*BB*NN, pixdst);

    for (int s = 1; s <= 6; ++s) {
        int* cur = corr + (s      % 3)*BB*NN;
        int* nxt = corr + ((s+1)  % 3)*BB*NN;
        int* rst = corr + ((s+2)  % 3)*BB*NN;
        k_step<<<dim3(((s+1)*NN + 255)/256, BB), blk, 0, stream>>>(
            rgb, depth, intr, poses, map, posconf, cur, nxt, rst, pixdst, s);
    }

    k_last<<<dim3((NN+255)/256, BB), blk, 0, stream>>>(
        rgb, depth, intr, poses, map, corr + (7 % 3)*BB*NN);
}